// Round 2
// baseline (56.271 us; speedup 1.0000x reference)
//
#include <hip/hip_runtime.h>
#include <hip/hip_bf16.h>

// PIXOR feature layer:
//   intensity[n] = mean_t vox_feats[n, t, 4]
//   out[b, 0, y, x] = 1.0   (occupancy)
//   out[b, 1, y, x] = intensity[n_last]  (last duplicate wins == max n wins)
//
// Structure:
//   k1: fused zero(out) + per-voxel intensity -> ws   (disjoint memory, one pass)
//   k2: atomicMax vote (n+1) into intensity plane (int view; 0 == empty)
//   k3: occ = 1.0; winner replaces its vote with float intensity

#define PX_NY 800
#define PX_NX 700
#define PX_T  32
#define PX_C  5

// Kernel 1: thread i < zq zeroes out4[i] (float4); thread zq+n computes
// intensity of voxel row n. Row = 160 floats = 40 float4s; channel-4 elements
// (idx % 5 == 4) appear only in float4s 5g+1..5g+4 at lanes x,y,z,w — the
// 5g+0 float4s carry none and are skipped (HW fetches the lines anyway, but
// this saves 20% of load instructions).
__global__ void __launch_bounds__(256)
pixor_zero_intens(const float4* __restrict__ vox4,
                  float4*       __restrict__ out4, int zq,
                  float*        __restrict__ intens, int N) {
    int i = blockIdx.x * blockDim.x + threadIdx.x;
    if (i < zq) {
        out4[i] = make_float4(0.f, 0.f, 0.f, 0.f);
    } else {
        int n = i - zq;
        if (n < N) {
            const float4* rp = vox4 + (size_t)n * (PX_T * PX_C / 4);
            float s = 0.f;
#pragma unroll
            for (int g = 0; g < 8; ++g) {
                float4 a = rp[g * 5 + 1];
                float4 b = rp[g * 5 + 2];
                float4 c = rp[g * 5 + 3];
                float4 d = rp[g * 5 + 4];
                s += (a.x + b.y) + (c.z + d.w);
            }
            intens[n] = s * (1.0f / (float)PX_T);
        }
    }
}

// Kernel 2: vote. Intensity plane (zeroed by k1) doubles as int buffer;
// winners hold max(n)+1 >= 1, empty cells hold 0.
__global__ void __launch_bounds__(256)
pixor_vote(const int* __restrict__ coords,
           int*       __restrict__ out_i,
           int N, int P) {
    int n = blockIdx.x * blockDim.x + threadIdx.x;
    if (n >= N) return;
    int4 c = ((const int4*)coords)[n];               // (b, z, y, x)
    int cell = c.x * (2 * P) + P + c.z * PX_NX + c.w;
    atomicMax(out_i + cell, n + 1);
}

// Kernel 3: occupancy + winner writes its float intensity over the vote.
// Losers read either winner's vote (n_win+1 != n+1) or winner's float bits
// (never a small positive int for this data) — race-safe.
__global__ void __launch_bounds__(256)
pixor_finalize(const int*   __restrict__ coords,
               const float* __restrict__ intens,
               float*       __restrict__ out,
               int N, int P) {
    int n = blockIdx.x * blockDim.x + threadIdx.x;
    if (n >= N) return;
    int4 c = ((const int4*)coords)[n];
    int base = c.x * (2 * P) + c.z * PX_NX + c.w;

    out[base] = 1.0f;                                // occupancy plane

    int* ip = (int*)out + base + P;                  // intensity plane cell
    if (*ip == n + 1) {
        *(float*)ip = intens[n];
    }
}

extern "C" void kernel_launch(void* const* d_in, const int* in_sizes, int n_in,
                              void* d_out, int out_size, void* d_ws, size_t ws_size,
                              hipStream_t stream) {
    const float* vox    = (const float*)d_in[0];   // [N, 32, 5] f32
    const int*   coords = (const int*)d_in[2];     // [N, 4] i32 (b, z, y, x)
    float* out = (float*)d_out;

    const int N = in_sizes[1];                     // 200000
    const int P = PX_NY * PX_NX;                   // 560000

    float* ws_int = (float*)d_ws;                  // N floats of scratch

    const int BLK = 256;

    // k1: fused zero + intensity
    const int zq    = out_size / 4;                // float4 count (out_size % 4 == 0)
    const int total = zq + N;
    pixor_zero_intens<<<(total + BLK - 1) / BLK, BLK, 0, stream>>>(
        (const float4*)vox, (float4*)out, zq, ws_int, N);

    const int grid = (N + BLK - 1) / BLK;
    pixor_vote<<<grid, BLK, 0, stream>>>(coords, (int*)out, N, P);
    pixor_finalize<<<grid, BLK, 0, stream>>>(coords, ws_int, out, N, P);
}